// Round 6
// baseline (185.028 us; speedup 1.0000x reference)
//
#include <hip/hip_runtime.h>

#define B_  4
#define S_  4096
#define DM  1024
#define DK  64
#define NSPLIT 8
#define KSPAN (S_ / NSPLIT)
#define QT  256                  // queries per flash block

typedef _Float16 half8  __attribute__((ext_vector_type(8)));
typedef _Float16 half4v __attribute__((ext_vector_type(4)));
typedef float    floatx4 __attribute__((ext_vector_type(4)));

// 0.125 (1/sqrt(64)) * log2(e): softmax in exp2 domain
#define QSCALE 0.18033688011112042f
#define EXP2F(x) __builtin_amdgcn_exp2f(x)

// ---------------------------------------------------------------------------
// One-time W transpose+convert into FRAGMENT-ORDERED layout:
//   Wt2[kt][pr][n][64 k-values]  (f16), kt = k-tile of 64, n = output dim.
// A B-fragment for (kt,pr,nt) is then one contiguous half8 at
//   ((kt*3+pr)*64 + nt*16 + l15)*64 + quad*8 (+32 for the second frag).
// ---------------------------------------------------------------------------
__global__ __launch_bounds__(256) void wt_kernel(
    const float* __restrict__ WQ, const float* __restrict__ WK,
    const float* __restrict__ WV, _Float16* __restrict__ Wt2)
{
    const int proj = blockIdx.y;
    const float* W = (proj == 0) ? WQ : (proj == 1) ? WK : WV;
    const int k0 = blockIdx.x * 64;
    const int t = threadIdx.x;
    __shared__ float T[64][68];

    #pragma unroll
    for (int p = 0; p < 4; p++) {
        int c = p * 256 + t;
        int k = c >> 4, n4 = (c & 15) * 4;
        float4 v = *(const float4*)(W + (size_t)(k0 + k) * DK + n4);
        T[k][n4 + 0] = v.x; T[k][n4 + 1] = v.y;
        T[k][n4 + 2] = v.z; T[k][n4 + 3] = v.w;
    }
    __syncthreads();

    const int n = t >> 2, kc = (t & 3) * 16;
    half8 h0, h1;
    #pragma unroll
    for (int j = 0; j < 8; j++) h0[j] = (_Float16)T[kc + j][n];
    #pragma unroll
    for (int j = 0; j < 8; j++) h1[j] = (_Float16)T[kc + 8 + j][n];
    _Float16* dst = Wt2 + (((size_t)blockIdx.x * 3 + proj) * 64 + n) * 64 + kc;
    *(half8*)(dst)     = h0;
    *(half8*)(dst + 8) = h1;
}

// ---------------------------------------------------------------------------
// Barrier-free fused QKV projection. No LDS at all:
//  - A-frags (X): lane reads 8 contiguous fp32 of its own row, cvt to f16.
//    Each wave owns 16 rows exclusively -> X read from HBM exactly once.
//  - B-frags (W): contiguous half8 loads from fragment-ordered Wt2
//    (384 KiB, L2-resident).
// 24 MFMA per wave per k-tile; X hand-double-buffered across k-tiles.
// ---------------------------------------------------------------------------
__global__ __launch_bounds__(256) void proj_mfma_kernel(
    const float* __restrict__ X, const _Float16* __restrict__ Wt2,
    const float* __restrict__ bQ, const float* __restrict__ bK,
    const float* __restrict__ bV,
    _Float16* __restrict__ Qh, _Float16* __restrict__ Kh,
    _Float16* __restrict__ Vt)
{
    const int t    = threadIdx.x;
    const int wave = t >> 6, lane = t & 63;
    const int quad = lane >> 4, l15 = lane & 15;
    const int row0 = blockIdx.x * 64 + wave * 16;   // 16 rows per wave

    const float* xp = X + (size_t)(row0 + l15) * DM + quad * 8;

    floatx4 acc[3][4];
    #pragma unroll
    for (int pr = 0; pr < 3; pr++)
        #pragma unroll
        for (int nt = 0; nt < 4; nt++)
            acc[pr][nt] = (floatx4){0.f, 0.f, 0.f, 0.f};

    float4 xa = *(const float4*)(xp + 0);
    float4 xb = *(const float4*)(xp + 4);
    float4 xc = *(const float4*)(xp + 32);
    float4 xd = *(const float4*)(xp + 36);

    for (int kt = 0; kt < DM / 64; kt++) {
        half8 xf0, xf1;
        xf0[0] = (_Float16)xa.x; xf0[1] = (_Float16)xa.y;
        xf0[2] = (_Float16)xa.z; xf0[3] = (_Float16)xa.w;
        xf0[4] = (_Float16)xb.x; xf0[5] = (_Float16)xb.y;
        xf0[6] = (_Float16)xb.z; xf0[7] = (_Float16)xb.w;
        xf1[0] = (_Float16)xc.x; xf1[1] = (_Float16)xc.y;
        xf1[2] = (_Float16)xc.z; xf1[3] = (_Float16)xc.w;
        xf1[4] = (_Float16)xd.x; xf1[5] = (_Float16)xd.y;
        xf1[6] = (_Float16)xd.z; xf1[7] = (_Float16)xd.w;

        if (kt + 1 < DM / 64) {
            const int kn = (kt + 1) * 64;
            xa = *(const float4*)(xp + kn + 0);
            xb = *(const float4*)(xp + kn + 4);
            xc = *(const float4*)(xp + kn + 32);
            xd = *(const float4*)(xp + kn + 36);
        }

        const _Float16* wb =
            Wt2 + ((size_t)kt * 3 * 64) * 64 + (size_t)l15 * 64 + quad * 8;
        #pragma unroll
        for (int pr = 0; pr < 3; pr++) {
            #pragma unroll
            for (int nt = 0; nt < 4; nt++) {
                const _Float16* wp = wb + (size_t)(pr * 64 + nt * 16) * 64;
                half8 w0 = *(const half8*)(wp);
                half8 w1 = *(const half8*)(wp + 32);
                floatx4 a = acc[pr][nt];
                a = __builtin_amdgcn_mfma_f32_16x16x32_f16(xf0, w0, a, 0, 0, 0);
                a = __builtin_amdgcn_mfma_f32_16x16x32_f16(xf1, w1, a, 0, 0, 0);
                acc[pr][nt] = a;
            }
        }
    }

    float bqv[4], bkv[4], bvv[4];
    #pragma unroll
    for (int nt = 0; nt < 4; nt++) {
        bqv[nt] = bQ[nt * 16 + l15];
        bkv[nt] = bK[nt * 16 + l15];
        bvv[nt] = bV[nt * 16 + l15];
    }

    const int orow = row0 + quad * 4;
    const int bidx = row0 >> 12;                 // 4096 rows / batch
    const int s0   = (row0 & (S_ - 1)) + quad * 4;
    #pragma unroll
    for (int nt = 0; nt < 4; nt++) {
        const int d = nt * 16 + l15;
        #pragma unroll
        for (int i = 0; i < 4; i++) {
            Qh[(size_t)(orow + i) * DK + d] =
                (_Float16)((acc[0][nt][i] + bqv[nt]) * QSCALE);
            Kh[(size_t)(orow + i) * DK + d] =
                (_Float16)(acc[1][nt][i] + bkv[nt]);
        }
        half4v hv;
        #pragma unroll
        for (int i = 0; i < 4; i++)
            hv[i] = (_Float16)(acc[2][nt][i] + bvv[nt]);
        *(half4v*)(Vt + (size_t)bidx * DK * S_ + (size_t)d * S_ + s0) = hv;
    }
}

// ---------------------------------------------------------------------------
// Flash v3 (unchanged from R5): 512 thr = 8 waves, 32 q/wave, split-K over
// NSPLIT ranges. No online max (logits O(5), exp2 fp32 can't overflow);
// per-lane rowsum, reduced once after the K-loop. Ps aliases Qs.
// ---------------------------------------------------------------------------
__global__ __launch_bounds__(512, 4) void flash_mfma_kernel(
    const _Float16* __restrict__ Qh, const _Float16* __restrict__ Kh,
    const _Float16* __restrict__ Vt, _Float16* __restrict__ Oph,
    float* __restrict__ Lp)
{
    const int b     = blockIdx.y;
    const int q0    = blockIdx.x * QT;
    const int split = blockIdx.z;
    const int kbase = split * KSPAN;
    const int t     = threadIdx.x;
    const int wave  = t >> 6, lane = t & 63;
    const int quad  = lane >> 4, l15 = lane & 15;

    __shared__ __align__(16) _Float16 Ks[64 * 72];
    __shared__ __align__(16) _Float16 Vs[64 * 72];        // [d][key]
    __shared__ __align__(16) _Float16 QsPs[QT * 72];      // Qs, then Ps

    const _Float16* Qb = Qh + ((size_t)b * S_ + q0) * DK;
    const _Float16* Kb = Kh + ((size_t)b * S_ + kbase) * DK;
    const _Float16* Vb = Vt + (size_t)b * DK * S_ + kbase;

    #pragma unroll
    for (int p = 0; p < 4; p++) {
        int c = p * 512 + t;
        int r = c >> 3, col = (c & 7) * 8;
        *(half8*)&QsPs[r * 72 + col] = *(const half8*)(Qb + r * 64 + col);
    }
    __syncthreads();
    half8 qf0[2], qf1[2];
    #pragma unroll
    for (int mt = 0; mt < 2; mt++) {
        const int r = wave * 32 + mt * 16 + l15;
        qf0[mt] = *(half8*)&QsPs[r * 72 + quad * 8];
        qf1[mt] = *(half8*)&QsPs[r * 72 + 32 + quad * 8];
    }
    __syncthreads();   // qf reads drained before Ps overwrites Qs

    _Float16* Pw = &QsPs[wave * 32 * 72];   // wave-private 32 rows

    floatx4 acc[2][4];
    float rs[2][4];
    #pragma unroll
    for (int mt = 0; mt < 2; mt++) {
        #pragma unroll
        for (int nt = 0; nt < 4; nt++) acc[mt][nt] = (floatx4){0.f,0.f,0.f,0.f};
        #pragma unroll
        for (int i = 0; i < 4; i++) rs[mt][i] = 0.f;
    }

    const int kr = t >> 3, kcol = (t & 7) * 8;
    half8 kreg = *(const half8*)(Kb + (size_t)kr * DK + kcol);
    half8 vreg = *(const half8*)(Vb + (size_t)kr * S_ + kcol);

    for (int k0 = 0; k0 < KSPAN; k0 += 64) {
        __syncthreads();
        *(half8*)&Ks[kr * 72 + kcol] = kreg;
        *(half8*)&Vs[kr * 72 + kcol] = vreg;
        __syncthreads();

        const int kn = k0 + 64;
        if (kn < KSPAN) {
            kreg = *(const half8*)(Kb + (size_t)(kn + kr) * DK + kcol);
            vreg = *(const half8*)(Vb + (size_t)kr * S_ + kn + kcol);
        }

        floatx4 sc[2][4];
        #pragma unroll
        for (int nt = 0; nt < 4; nt++) {
            half8 kf0 = *(half8*)&Ks[(nt * 16 + l15) * 72 + quad * 8];
            half8 kf1 = *(half8*)&Ks[(nt * 16 + l15) * 72 + 32 + quad * 8];
            #pragma unroll
            for (int mt = 0; mt < 2; mt++) {
                floatx4 z = (floatx4){0.f, 0.f, 0.f, 0.f};
                z = __builtin_amdgcn_mfma_f32_16x16x32_f16(qf0[mt], kf0, z, 0, 0, 0);
                z = __builtin_amdgcn_mfma_f32_16x16x32_f16(qf1[mt], kf1, z, 0, 0, 0);
                sc[mt][nt] = z;
            }
        }

        #pragma unroll
        for (int mt = 0; mt < 2; mt++)
            #pragma unroll
            for (int nt = 0; nt < 4; nt++)
                #pragma unroll
                for (int i = 0; i < 4; i++) {
                    float pe = EXP2F(sc[mt][nt][i]);
                    rs[mt][i] += pe;
                    Pw[(mt * 16 + quad * 4 + i) * 72 + nt * 16 + l15] = (_Float16)pe;
                }

        half8 pf0[2], pf1[2];
        #pragma unroll
        for (int mt = 0; mt < 2; mt++) {
            pf0[mt] = *(half8*)&Pw[(mt * 16 + l15) * 72 + quad * 8];
            pf1[mt] = *(half8*)&Pw[(mt * 16 + l15) * 72 + 32 + quad * 8];
        }

        #pragma unroll
        for (int nt = 0; nt < 4; nt++) {
            half8 vf0 = *(half8*)&Vs[(nt * 16 + l15) * 72 + quad * 8];
            half8 vf1 = *(half8*)&Vs[(nt * 16 + l15) * 72 + 32 + quad * 8];
            #pragma unroll
            for (int mt = 0; mt < 2; mt++) {
                floatx4 a = acc[mt][nt];
                a = __builtin_amdgcn_mfma_f32_16x16x32_f16(pf0[mt], vf0, a, 0, 0, 0);
                a = __builtin_amdgcn_mfma_f32_16x16x32_f16(pf1[mt], vf1, a, 0, 0, 0);
                acc[mt][nt] = a;
            }
        }
    }

    const size_t prow = (size_t)split * B_ * S_ + (size_t)b * S_ + q0;
    #pragma unroll
    for (int mt = 0; mt < 2; mt++) {
        float inv[4];
        #pragma unroll
        for (int i = 0; i < 4; i++) {
            float r = rs[mt][i];
            #pragma unroll
            for (int off = 1; off < 16; off <<= 1)
                r += __shfl_xor(r, off, 64);
            rs[mt][i] = r;
            inv[i] = 1.0f / r;
        }
        const int rbase = wave * 32 + mt * 16 + quad * 4;
        #pragma unroll
        for (int nt = 0; nt < 4; nt++)
            #pragma unroll
            for (int i = 0; i < 4; i++)
                Oph[(prow + rbase + i) * DK + nt * 16 + l15] =
                    (_Float16)(acc[mt][nt][i] * inv[i]);
        if (l15 == 0) {
            #pragma unroll
            for (int i = 0; i < 4; i++)
                Lp[prow + rbase + i] = rs[mt][i];
        }
    }
}

// ---------------------------------------------------------------------------
// Combine: O[r] = sum_s l_s * Ohat_s[r] / sum_s l_s.  16 rows x 16 lanes.
// ---------------------------------------------------------------------------
__global__ __launch_bounds__(256) void combine_kernel(
    const _Float16* __restrict__ Oph, const float* __restrict__ Lp,
    float* __restrict__ O)
{
    const int r  = blockIdx.x * 16 + (threadIdx.x >> 4);
    const int d4 = (threadIdx.x & 15) * 4;
    const int NR = B_ * S_;

    float lw[NSPLIT], lsum = 0.f;
    #pragma unroll
    for (int s = 0; s < NSPLIT; s++) {
        lw[s] = Lp[(size_t)s * NR + r];
        lsum += lw[s];
    }
    const float inv = 1.0f / lsum;

    float o[4] = {0.f, 0.f, 0.f, 0.f};
    #pragma unroll
    for (int s = 0; s < NSPLIT; s++) {
        half4v h = *(const half4v*)(Oph + ((size_t)s * NR + r) * DK + d4);
        const float w = lw[s];
        #pragma unroll
        for (int j = 0; j < 4; j++) o[j] += w * (float)h[j];
    }
    float4 out;
    out.x = o[0] * inv; out.y = o[1] * inv;
    out.z = o[2] * inv; out.w = o[3] * inv;
    *(float4*)(O + (size_t)r * DK + d4) = out;
}

// ---------------------------------------------------------------------------
extern "C" void kernel_launch(void* const* d_in, const int* in_sizes, int n_in,
                              void* d_out, int out_size, void* d_ws, size_t ws_size,
                              hipStream_t stream)
{
    const float* X  = (const float*)d_in[0];
    // cultural path (d_in[1], d_in[8..10]) cancels in softmax -> unused
    const float* WQ = (const float*)d_in[2];
    const float* bQ = (const float*)d_in[3];
    const float* WK = (const float*)d_in[4];
    const float* bK = (const float*)d_in[5];
    const float* WV = (const float*)d_in[6];
    const float* bV = (const float*)d_in[7];

    char* ws = (char*)d_ws;
    _Float16* Qh  = (_Float16*)ws;  ws += (size_t)B_ * S_ * DK * 2;   // 2 MiB
    _Float16* Kh  = (_Float16*)ws;  ws += (size_t)B_ * S_ * DK * 2;
    _Float16* Vt  = (_Float16*)ws;  ws += (size_t)B_ * S_ * DK * 2;
    _Float16* Wt2 = (_Float16*)ws;  ws += (size_t)3 * 64 * DM * 2;    // 384 KiB
    _Float16* Oph = (_Float16*)ws;  ws += (size_t)NSPLIT * B_ * S_ * DK * 2; // 16 MiB
    float* Lp     = (float*)ws;

    wt_kernel<<<dim3(DM / 64, 3), 256, 0, stream>>>(WQ, WK, WV, Wt2);

    proj_mfma_kernel<<<dim3((B_ * S_) / 64), 256, 0, stream>>>(
        X, Wt2, bQ, bK, bV, Qh, Kh, Vt);

    flash_mfma_kernel<<<dim3(S_ / QT, B_, NSPLIT), 512, 0, stream>>>(
        Qh, Kh, Vt, Oph, Lp);

    combine_kernel<<<dim3((B_ * S_) / 16), 256, 0, stream>>>(
        Oph, Lp, (float*)d_out);
}